// Round 5
// baseline (72.532 us; speedup 1.0000x reference)
//
#include <hip/hip_runtime.h>

#define BATCH 16
#define TT 60
#define NCLS 80
// 512 cells per block: lvl0 ceil(17328/512)=34, lvl1 ceil(4332/512)=9, lvl2 ceil(1083/512)=3
#define NB0 34
#define NB1 9
#define NB2 3
#define NBX (NB0 + NB1 + NB2)
#define NBLK_TOT (NBX * BATCH)

__constant__ float c_aw[9] = {12.f,19.f,40.f,36.f,76.f,72.f,142.f,192.f,459.f};
__constant__ float c_ah[9] = {16.f,36.f,28.f,75.f,55.f,146.f,110.f,243.f,401.f};

__device__ __forceinline__ float sigf(float x){ return 1.0f/(1.0f+expf(-x)); }
__device__ __forceinline__ float clogf_(float x){ return fmaxf(logf(x), -100.0f); }
__device__ __forceinline__ float bcef(float p, float t){
    return -(t*clogf_(p) + (1.0f-t)*clogf_(1.0f-p));
}

// Fully fused, 2 cells/thread, last-block-done finish.
// ws layout: ws[0..4] = float partials (xy, wh, obj, cls, l2); ((uint*)ws)[8] = block counter.
__global__ __launch_bounds__(256) void main_kernel(
    const float* __restrict__ x0, const float* __restrict__ x1,
    const float* __restrict__ x2, const float* __restrict__ labels,
    float* __restrict__ ws, float* __restrict__ out)
{
    const int bx = blockIdx.x, b = blockIdx.y, tid = threadIdx.x;
    int lvl, lb, fs;
    const float* x;
    if (bx < NB0)            { lvl = 0; lb = bx;             x = x0; fs = 76; }
    else if (bx < NB0 + NB1) { lvl = 1; lb = bx - NB0;       x = x1; fs = 38; }
    else                     { lvl = 2; lb = bx - NB0 - NB1; x = x2; fs = 19; }
    const float invs = 1.0f/(float)(8 << lvl);     // exact (pow2)
    const int fs2 = fs*fs;
    const int ncell = 3*fs2;
    const int lin0 = lb*512 + tid;
    const int lin1 = lin0 + 256;

    __shared__ float  s_atan[9];
    __shared__ float4 s_box[TT];
    __shared__ int    s_mcell[TT], s_mcls[TT];
    __shared__ float  s_vx[TT], s_vy[TT], s_vw[TT], s_vh[TT], s_sc[TT];
    __shared__ int    s_nv, s_nm, s_qn, s_last;
    __shared__ int    s_qoff[TT], s_qcls[TT];

    // ---- stage A: issue both cells' channel loads early
    float v0a=0,v1a=0,v2a=0,v3a=0,v4a=0, v0b=0,v1b=0,v2b=0,v3b=0,v4b=0;
    int a0=0,rem0=0,ci0=0,cj0=0, a1=0,rem1=0,ci1=0,cj1=0;
    if (lin0 < ncell) {
        a0 = lin0/fs2; rem0 = lin0 - a0*fs2; cj0 = rem0/fs; ci0 = rem0 - cj0*fs;
        const float* xb = x + ((size_t)b*255 + a0*85)*(size_t)fs2 + rem0;
        v0a = xb[0]; v1a = xb[(size_t)fs2]; v2a = xb[(size_t)2*fs2];
        v3a = xb[(size_t)3*fs2]; v4a = xb[(size_t)4*fs2];
    }
    if (lin1 < ncell) {
        a1 = lin1/fs2; rem1 = lin1 - a1*fs2; cj1 = rem1/fs; ci1 = rem1 - cj1*fs;
        const float* xb = x + ((size_t)b*255 + a1*85)*(size_t)fs2 + rem1;
        v0b = xb[0]; v1b = xb[(size_t)fs2]; v2b = xb[(size_t)2*fs2];
        v3b = xb[(size_t)3*fs2]; v4b = xb[(size_t)4*fs2];
    }
    float l0=0,l1=0,l2=0,l3=0,l4=0;
    if (tid < TT) {
        const float* lab = labels + ((size_t)b*TT + tid)*5;
        l0=lab[0]; l1=lab[1]; l2=lab[2]; l3=lab[3]; l4=lab[4];
    }
    if (tid < 9) s_atan[tid] = atanf(c_aw[tid]/c_ah[tid]);   // stride-invariant
    if (tid == 0) s_qn = 0;
    __syncthreads();

    // ---- stage B: per-truth prep (wave 0, lanes = truths)
    if (tid < 64) {
        bool valid=false, best=false;
        float tx=0,ty=0,tw=0,th=0;
        int best_all=0;
        if (tid < TT) {
            valid = ((((l0+l1)+l2)+l3)+l4) > 0.0f;
            tx = (l2+l0)*(0.5f*invs);
            ty = (l3+l1)*(0.5f*invs);
            tw = (l2-l0)*invs;
            th = (l3-l1)*invs;
            if (valid) {
                float ta = atanf(tw/th);
                float twth = tw*th;
                float bestv = 0.0f;
                for (int k=0;k<9;k++){
                    float wb=c_aw[k]*invs, hb=c_ah[k]*invs;
                    float iw=fminf(tw,wb), ih=fminf(th,hb);
                    float en=(iw>0.f && ih>0.f)?1.f:0.f;
                    float ai=iw*ih*en;
                    float au=twth+wb*hb-ai;
                    float iou=ai/au;
                    float mw=fmaxf(tw,wb), mh=fmaxf(th,hb);
                    float c2=mw*mw+mh*mh+1e-16f;
                    float rho2=((tw-wb)*(tw-wb)+(th-hb)*(th-hb))*0.25f;
                    float da=ta-s_atan[k];
                    float v=0.40528473456935109f*da*da;     // 4/pi^2
                    float alpha=v/((1.f-iou)+v);
                    float cv=iou-(rho2/c2+v*alpha);
                    if (k==0 || cv>bestv){ bestv=cv; best_all=k; }  // first-max wins
                }
            }
        }
        int bn = best_all % 3;
        best = valid && ((best_all/3) == lvl);
        unsigned long long vm = __ballot(valid);
        unsigned long long bm = __ballot(best);
        unsigned long long below = (tid==0) ? 0ULL : ((1ULL<<tid)-1ULL);
        if (valid){
            int r = __popcll(vm & below);
            s_box[r] = make_float4(tx-0.5f*tw, ty-0.5f*th, tx+0.5f*tw, ty+0.5f*th);
        }
        if (best){
            int r = __popcll(bm & below);
            int ti=(int)tx, tj=(int)ty;
            int ii = ti<0?0:(ti>fs-1?fs-1:ti);
            int jj = tj<0?0:(tj>fs-1?fs-1:tj);
            s_mcell[r] = (bn*fs+jj)*fs+ii;
            s_mcls[r]  = (int)l4;
            s_sc[r]    = sqrtf(2.f - tw*th/(float)(fs*fs));
            s_vx[r]    = tx - truncf(tx);
            s_vy[r]    = ty - truncf(ty);
            float aw = c_aw[3*lvl+bn]*invs, ah = c_ah[3*lvl+bn]*invs;
            s_vw[r]    = logf(tw/aw + 1e-16f);
            s_vh[r]    = logf(th/ah + 1e-16f);
        }
        if (tid==0){ s_nv = __popcll(vm); s_nm = __popcll(bm); }
    }
    __syncthreads();

    // ---- stage C: per-cell loss for both cells in one pass
    const int nv = s_nv, nm = s_nm;
    float lxy=0.f, lwh=0.f, lobj=0.f, lcls=0.f, ll2=0.f;
    const bool c0 = (lin0 < ncell), c1 = (lin1 < ncell);
    if (c0 | c1) {
        const float sxa = sigf(v0a), sya = sigf(v1a), soa = sigf(v4a);
        const float sxb = sigf(v0b), syb = sigf(v1b), sob = sigf(v4b);
        const float awa = c_aw[3*lvl+a0]*invs, aha = c_ah[3*lvl+a0]*invs;
        const float awb = c_aw[3*lvl+a1]*invs, ahb = c_ah[3*lvl+a1]*invs;
        const float pxa = sxa + (float)ci0, pya = sya + (float)cj0;
        const float pxb = sxb + (float)ci1, pyb = syb + (float)cj1;
        const float pwa = expf(v2a)*awa, pha = expf(v3a)*aha;
        const float pwb = expf(v2b)*awb, phb = expf(v3b)*ahb;
        const float apa = pwa*pha, apb = pwb*phb;

        int mt0 = -1, mt1 = -1;                    // last match wins
        for (int k=0;k<nm;k++){
            int mc = s_mcell[k];
            if (mc == lin0) mt0 = k;
            if (mc == lin1) mt1 = k;
        }

        bool iga = false, igb = false;             // IoU>0.5 <=> 3*ai > ap+at
        if (nm > 0) {
            const float xla = pxa-0.5f*pwa, xra = pxa+0.5f*pwa;
            const float yla = pya-0.5f*pha, yra = pya+0.5f*pha;
            const float xlb = pxb-0.5f*pwb, xrb = pxb+0.5f*pwb;
            const float ylb = pyb-0.5f*phb, yrb = pyb+0.5f*phb;
            #pragma unroll 4
            for (int t=0;t<nv;t++){
                float4 tb = s_box[t];
                float at2 = (tb.z-tb.x)*(tb.w-tb.y);
                float wa = fminf(xra,tb.z) - fmaxf(xla,tb.x);
                float ha = fminf(yra,tb.w) - fmaxf(yla,tb.y);
                float wb = fminf(xrb,tb.z) - fmaxf(xlb,tb.x);
                float hb = fminf(yrb,tb.w) - fmaxf(ylb,tb.y);
                iga = iga || ((wa>0.f)&&(ha>0.f)&&(3.f*(wa*ha) > apa+at2));
                igb = igb || ((wb>0.f)&&(hb>0.f)&&(3.f*(wb*hb) > apb+at2));
            }
        }
        // cell 0
        if (c0) {
            float om = (nm>0) ? (iga ? 0.f : 1.f) : 1.f;
            float t4 = 0.f;
            if (mt0 >= 0){ om = 1.f; t4 = 1.f; }
            float oo = soa*om, to = t4*om;
            lobj += bcef(oo, to);
            float d = oo - to; ll2 += d*d;
            if (mt0 >= 0) {
                float sc = s_sc[mt0], w2 = sc*sc;
                float mvx = s_vx[mt0], mvy = s_vy[mt0];
                lxy += w2*(bcef(sxa,mvx) + bcef(sya,mvy));
                float dx = sxa-mvx, dy = sya-mvy;
                float dw = sc*(v2a - s_vw[mt0]);
                float dh = sc*(v3a - s_vh[mt0]);
                lwh += 0.5f*(dw*dw + dh*dh);
                ll2 += dx*dx + dy*dy + dw*dw + dh*dh;
                int qi = atomicAdd(&s_qn, 1);
                s_qoff[qi] = (a0*85+5)*fs2 + rem0;
                s_qcls[qi] = s_mcls[mt0];
            }
        }
        // cell 1
        if (c1) {
            float om = (nm>0) ? (igb ? 0.f : 1.f) : 1.f;
            float t4 = 0.f;
            if (mt1 >= 0){ om = 1.f; t4 = 1.f; }
            float oo = sob*om, to = t4*om;
            lobj += bcef(oo, to);
            float d = oo - to; ll2 += d*d;
            if (mt1 >= 0) {
                float sc = s_sc[mt1], w2 = sc*sc;
                float mvx = s_vx[mt1], mvy = s_vy[mt1];
                lxy += w2*(bcef(sxb,mvx) + bcef(syb,mvy));
                float dx = sxb-mvx, dy = syb-mvy;
                float dw = sc*(v2b - s_vw[mt1]);
                float dh = sc*(v3b - s_vh[mt1]);
                lwh += 0.5f*(dw*dw + dh*dh);
                ll2 += dx*dx + dy*dy + dw*dw + dh*dh;
                int qi = atomicAdd(&s_qn, 1);
                s_qoff[qi] = (a1*85+5)*fs2 + rem1;
                s_qcls[qi] = s_mcls[mt1];
            }
        }
    }
    __syncthreads();

    // ---- stage D: class channels, one wave per queued match
    const int wid = tid>>6, ln = tid&63;
    const int qn = s_qn;
    for (int it = wid; it < qn; it += 4){
        const size_t base = (size_t)b*255*(size_t)fs2 + (size_t)s_qoff[it];
        const int cc = s_qcls[it];
        float p = sigf(x[base + (size_t)ln*fs2]);
        float tt = (ln==cc) ? 1.f : 0.f;
        lcls += bcef(p, tt);
        float dd = p - tt; ll2 += dd*dd;
        if (ln < NCLS-64) {
            int c = 64+ln;
            p = sigf(x[base + (size_t)c*fs2]);
            tt = (c==cc) ? 1.f : 0.f;
            lcls += bcef(p, tt);
            dd = p - tt; ll2 += dd*dd;
        }
    }

    // ---- block reduction + global accumulate + last-block finish
    for (int off=32; off>0; off>>=1){
        lxy  += __shfl_down(lxy,  off);
        lwh  += __shfl_down(lwh,  off);
        lobj += __shfl_down(lobj, off);
        lcls += __shfl_down(lcls, off);
        ll2  += __shfl_down(ll2,  off);
    }
    __shared__ float red[4][5];
    if (ln == 0){ red[wid][0]=lxy; red[wid][1]=lwh; red[wid][2]=lobj; red[wid][3]=lcls; red[wid][4]=ll2; }
    __syncthreads();
    if (tid == 0){
        atomicAdd(&ws[0], red[0][0]+red[1][0]+red[2][0]+red[3][0]);
        atomicAdd(&ws[1], red[0][1]+red[1][1]+red[2][1]+red[3][1]);
        atomicAdd(&ws[2], red[0][2]+red[1][2]+red[2][2]+red[3][2]);
        atomicAdd(&ws[3], red[0][3]+red[1][3]+red[2][3]+red[3][3]);
        atomicAdd(&ws[4], red[0][4]+red[1][4]+red[2][4]+red[3][4]);
        __threadfence();
        unsigned int old = atomicAdd((unsigned int*)ws + 8, 1u);
        s_last = (old == (unsigned int)(NBLK_TOT - 1)) ? 1 : 0;
    }
    __syncthreads();
    if (s_last && tid == 0){
        float t_xy  = atomicAdd(&ws[0], 0.0f);
        float t_wh  = atomicAdd(&ws[1], 0.0f);
        float t_obj = atomicAdd(&ws[2], 0.0f);
        float t_cls = atomicAdd(&ws[3], 0.0f);
        float t_l2  = atomicAdd(&ws[4], 0.0f);
        out[0] = t_xy + t_wh + t_obj + t_cls;
        out[1] = t_xy; out[2] = t_wh; out[3] = t_obj; out[4] = t_cls; out[5] = t_l2;
    }
}

extern "C" void kernel_launch(void* const* d_in, const int* in_sizes, int n_in,
                              void* d_out, int out_size, void* d_ws, size_t ws_size,
                              hipStream_t stream) {
    const float* x0 = (const float*)d_in[0];
    const float* x1 = (const float*)d_in[1];
    const float* x2 = (const float*)d_in[2];
    const float* labels = (const float*)d_in[3];
    float* out = (float*)d_out;
    float* ws = (float*)d_ws;

    hipMemsetAsync(ws, 0, 64, stream);   // zero 5 partials + counter (capture-legal memset node)
    main_kernel<<<dim3(NBX, BATCH), 256, 0, stream>>>(x0, x1, x2, labels, ws, out);
}

// Round 6
// 25.944 us; speedup vs baseline: 2.7957x; 2.7957x over previous
//
#include <hip/hip_runtime.h>

#define BATCH 16
#define TT 60
#define NCLS 80
// 512 cells per block: lvl0 ceil(17328/512)=34, lvl1 ceil(4332/512)=9, lvl2 ceil(1083/512)=3
#define NB0 34
#define NB1 9
#define NB2 3
#define NBX (NB0 + NB1 + NB2)
#define NBLK (NBX * BATCH)

__constant__ float c_aw[9] = {12.f,19.f,40.f,36.f,76.f,72.f,142.f,192.f,459.f};
__constant__ float c_ah[9] = {16.f,36.f,28.f,75.f,55.f,146.f,110.f,243.f,401.f};

__device__ __forceinline__ float sigf(float x){ return 1.0f/(1.0f+expf(-x)); }
__device__ __forceinline__ float clogf_(float x){ return fmaxf(logf(x), -100.0f); }
__device__ __forceinline__ float bcef(float p, float t){
    return -(t*clogf_(p) + (1.0f-t)*clogf_(1.0f-p));
}

// 2 cells/thread; finish = per-block partial stores + fin_kernel (R4 mechanism).
__global__ __launch_bounds__(256) void main_kernel(
    const float* __restrict__ x0, const float* __restrict__ x1,
    const float* __restrict__ x2, const float* __restrict__ labels,
    float* __restrict__ ws)
{
    const int bx = blockIdx.x, b = blockIdx.y, tid = threadIdx.x;
    int lvl, lb, fs;
    const float* x;
    if (bx < NB0)            { lvl = 0; lb = bx;             x = x0; fs = 76; }
    else if (bx < NB0 + NB1) { lvl = 1; lb = bx - NB0;       x = x1; fs = 38; }
    else                     { lvl = 2; lb = bx - NB0 - NB1; x = x2; fs = 19; }
    const float invs = 1.0f/(float)(8 << lvl);     // exact (pow2)
    const int fs2 = fs*fs;
    const int ncell = 3*fs2;
    const int lin0 = lb*512 + tid;
    const int lin1 = lin0 + 256;

    __shared__ float  s_atan[9];
    __shared__ float4 s_box[TT];
    __shared__ int    s_mcell[TT], s_mcls[TT];
    __shared__ float  s_vx[TT], s_vy[TT], s_vw[TT], s_vh[TT], s_sc[TT];
    __shared__ int    s_nv, s_nm, s_qn;
    __shared__ int    s_qoff[TT], s_qcls[TT];

    // ---- stage A: issue both cells' channel loads early
    float v0a=0,v1a=0,v2a=0,v3a=0,v4a=0, v0b=0,v1b=0,v2b=0,v3b=0,v4b=0;
    int a0=0,rem0=0,ci0=0,cj0=0, a1=0,rem1=0,ci1=0,cj1=0;
    if (lin0 < ncell) {
        a0 = lin0/fs2; rem0 = lin0 - a0*fs2; cj0 = rem0/fs; ci0 = rem0 - cj0*fs;
        const float* xb = x + ((size_t)b*255 + a0*85)*(size_t)fs2 + rem0;
        v0a = xb[0]; v1a = xb[(size_t)fs2]; v2a = xb[(size_t)2*fs2];
        v3a = xb[(size_t)3*fs2]; v4a = xb[(size_t)4*fs2];
    }
    if (lin1 < ncell) {
        a1 = lin1/fs2; rem1 = lin1 - a1*fs2; cj1 = rem1/fs; ci1 = rem1 - cj1*fs;
        const float* xb = x + ((size_t)b*255 + a1*85)*(size_t)fs2 + rem1;
        v0b = xb[0]; v1b = xb[(size_t)fs2]; v2b = xb[(size_t)2*fs2];
        v3b = xb[(size_t)3*fs2]; v4b = xb[(size_t)4*fs2];
    }
    float l0=0,l1=0,l2=0,l3=0,l4=0;
    if (tid < TT) {
        const float* lab = labels + ((size_t)b*TT + tid)*5;
        l0=lab[0]; l1=lab[1]; l2=lab[2]; l3=lab[3]; l4=lab[4];
    }
    if (tid < 9) s_atan[tid] = atanf(c_aw[tid]/c_ah[tid]);   // stride-invariant
    if (tid == 0) s_qn = 0;
    __syncthreads();

    // ---- stage B: per-truth prep (wave 0, lanes = truths)
    if (tid < 64) {
        bool valid=false, best=false;
        float tx=0,ty=0,tw=0,th=0;
        int best_all=0;
        if (tid < TT) {
            valid = ((((l0+l1)+l2)+l3)+l4) > 0.0f;
            tx = (l2+l0)*(0.5f*invs);
            ty = (l3+l1)*(0.5f*invs);
            tw = (l2-l0)*invs;
            th = (l3-l1)*invs;
            if (valid) {
                float ta = atanf(tw/th);
                float twth = tw*th;
                float bestv = 0.0f;
                for (int k=0;k<9;k++){
                    float wb=c_aw[k]*invs, hb=c_ah[k]*invs;
                    float iw=fminf(tw,wb), ih=fminf(th,hb);
                    float en=(iw>0.f && ih>0.f)?1.f:0.f;
                    float ai=iw*ih*en;
                    float au=twth+wb*hb-ai;
                    float iou=ai/au;
                    float mw=fmaxf(tw,wb), mh=fmaxf(th,hb);
                    float c2=mw*mw+mh*mh+1e-16f;
                    float rho2=((tw-wb)*(tw-wb)+(th-hb)*(th-hb))*0.25f;
                    float da=ta-s_atan[k];
                    float v=0.40528473456935109f*da*da;     // 4/pi^2
                    float alpha=v/((1.f-iou)+v);
                    float cv=iou-(rho2/c2+v*alpha);
                    if (k==0 || cv>bestv){ bestv=cv; best_all=k; }  // first-max wins
                }
            }
        }
        int bn = best_all % 3;
        best = valid && ((best_all/3) == lvl);
        unsigned long long vm = __ballot(valid);
        unsigned long long bm = __ballot(best);
        unsigned long long below = (tid==0) ? 0ULL : ((1ULL<<tid)-1ULL);
        if (valid){
            int r = __popcll(vm & below);
            s_box[r] = make_float4(tx-0.5f*tw, ty-0.5f*th, tx+0.5f*tw, ty+0.5f*th);
        }
        if (best){
            int r = __popcll(bm & below);
            int ti=(int)tx, tj=(int)ty;
            int ii = ti<0?0:(ti>fs-1?fs-1:ti);
            int jj = tj<0?0:(tj>fs-1?fs-1:tj);
            s_mcell[r] = (bn*fs+jj)*fs+ii;
            s_mcls[r]  = (int)l4;
            s_sc[r]    = sqrtf(2.f - tw*th/(float)(fs*fs));
            s_vx[r]    = tx - truncf(tx);
            s_vy[r]    = ty - truncf(ty);
            float aw = c_aw[3*lvl+bn]*invs, ah = c_ah[3*lvl+bn]*invs;
            s_vw[r]    = logf(tw/aw + 1e-16f);
            s_vh[r]    = logf(th/ah + 1e-16f);
        }
        if (tid==0){ s_nv = __popcll(vm); s_nm = __popcll(bm); }
    }
    __syncthreads();

    // ---- stage C: per-cell loss for both cells in one pass
    const int nv = s_nv, nm = s_nm;
    float lxy=0.f, lwh=0.f, lobj=0.f, lcls=0.f, ll2=0.f;
    const bool c0 = (lin0 < ncell), c1 = (lin1 < ncell);
    if (c0 | c1) {
        const float sxa = sigf(v0a), sya = sigf(v1a), soa = sigf(v4a);
        const float sxb = sigf(v0b), syb = sigf(v1b), sob = sigf(v4b);
        const float awa = c_aw[3*lvl+a0]*invs, aha = c_ah[3*lvl+a0]*invs;
        const float awb = c_aw[3*lvl+a1]*invs, ahb = c_ah[3*lvl+a1]*invs;
        const float pxa = sxa + (float)ci0, pya = sya + (float)cj0;
        const float pxb = sxb + (float)ci1, pyb = syb + (float)cj1;
        const float pwa = expf(v2a)*awa, pha = expf(v3a)*aha;
        const float pwb = expf(v2b)*awb, phb = expf(v3b)*ahb;
        const float apa = pwa*pha, apb = pwb*phb;

        int mt0 = -1, mt1 = -1;                    // last match wins
        for (int k=0;k<nm;k++){
            int mc = s_mcell[k];
            if (mc == lin0) mt0 = k;
            if (mc == lin1) mt1 = k;
        }

        bool iga = false, igb = false;             // IoU>0.5 <=> 3*ai > ap+at
        if (nm > 0) {
            const float xla = pxa-0.5f*pwa, xra = pxa+0.5f*pwa;
            const float yla = pya-0.5f*pha, yra = pya+0.5f*pha;
            const float xlb = pxb-0.5f*pwb, xrb = pxb+0.5f*pwb;
            const float ylb = pyb-0.5f*phb, yrb = pyb+0.5f*phb;
            #pragma unroll 4
            for (int t=0;t<nv;t++){
                float4 tb = s_box[t];
                float at2 = (tb.z-tb.x)*(tb.w-tb.y);
                float wa = fminf(xra,tb.z) - fmaxf(xla,tb.x);
                float ha = fminf(yra,tb.w) - fmaxf(yla,tb.y);
                float wb = fminf(xrb,tb.z) - fmaxf(xlb,tb.x);
                float hb = fminf(yrb,tb.w) - fmaxf(ylb,tb.y);
                iga = iga || ((wa>0.f)&&(ha>0.f)&&(3.f*(wa*ha) > apa+at2));
                igb = igb || ((wb>0.f)&&(hb>0.f)&&(3.f*(wb*hb) > apb+at2));
            }
        }
        // cell 0
        if (c0) {
            float om = (nm>0) ? (iga ? 0.f : 1.f) : 1.f;
            float t4 = 0.f;
            if (mt0 >= 0){ om = 1.f; t4 = 1.f; }
            float oo = soa*om, to = t4*om;
            lobj += bcef(oo, to);
            float d = oo - to; ll2 += d*d;
            if (mt0 >= 0) {
                float sc = s_sc[mt0], w2 = sc*sc;
                float mvx = s_vx[mt0], mvy = s_vy[mt0];
                lxy += w2*(bcef(sxa,mvx) + bcef(sya,mvy));
                float dx = sxa-mvx, dy = sya-mvy;
                float dw = sc*(v2a - s_vw[mt0]);
                float dh = sc*(v3a - s_vh[mt0]);
                lwh += 0.5f*(dw*dw + dh*dh);
                ll2 += dx*dx + dy*dy + dw*dw + dh*dh;
                int qi = atomicAdd(&s_qn, 1);
                s_qoff[qi] = (a0*85+5)*fs2 + rem0;
                s_qcls[qi] = s_mcls[mt0];
            }
        }
        // cell 1
        if (c1) {
            float om = (nm>0) ? (igb ? 0.f : 1.f) : 1.f;
            float t4 = 0.f;
            if (mt1 >= 0){ om = 1.f; t4 = 1.f; }
            float oo = sob*om, to = t4*om;
            lobj += bcef(oo, to);
            float d = oo - to; ll2 += d*d;
            if (mt1 >= 0) {
                float sc = s_sc[mt1], w2 = sc*sc;
                float mvx = s_vx[mt1], mvy = s_vy[mt1];
                lxy += w2*(bcef(sxb,mvx) + bcef(syb,mvy));
                float dx = sxb-mvx, dy = syb-mvy;
                float dw = sc*(v2b - s_vw[mt1]);
                float dh = sc*(v3b - s_vh[mt1]);
                lwh += 0.5f*(dw*dw + dh*dh);
                ll2 += dx*dx + dy*dy + dw*dw + dh*dh;
                int qi = atomicAdd(&s_qn, 1);
                s_qoff[qi] = (a1*85+5)*fs2 + rem1;
                s_qcls[qi] = s_mcls[mt1];
            }
        }
    }
    __syncthreads();

    // ---- stage D: class channels, one wave per queued match
    const int wid = tid>>6, ln = tid&63;
    const int qn = s_qn;
    for (int it = wid; it < qn; it += 4){
        const size_t base = (size_t)b*255*(size_t)fs2 + (size_t)s_qoff[it];
        const int cc = s_qcls[it];
        float p = sigf(x[base + (size_t)ln*fs2]);
        float tt = (ln==cc) ? 1.f : 0.f;
        lcls += bcef(p, tt);
        float dd = p - tt; ll2 += dd*dd;
        if (ln < NCLS-64) {
            int c = 64+ln;
            p = sigf(x[base + (size_t)c*fs2]);
            tt = (c==cc) ? 1.f : 0.f;
            lcls += bcef(p, tt);
            dd = p - tt; ll2 += dd*dd;
        }
    }

    // ---- block reduction + per-block partial stores (R4 finish, no atomics/fence)
    for (int off=32; off>0; off>>=1){
        lxy  += __shfl_down(lxy,  off);
        lwh  += __shfl_down(lwh,  off);
        lobj += __shfl_down(lobj, off);
        lcls += __shfl_down(lcls, off);
        ll2  += __shfl_down(ll2,  off);
    }
    __shared__ float red[4][5];
    if (ln == 0){ red[wid][0]=lxy; red[wid][1]=lwh; red[wid][2]=lobj; red[wid][3]=lcls; red[wid][4]=ll2; }
    __syncthreads();
    if (tid == 0){
        const int blk = b*NBX + bx;
        ws[0*NBLK + blk] = red[0][0]+red[1][0]+red[2][0]+red[3][0];
        ws[1*NBLK + blk] = red[0][1]+red[1][1]+red[2][1]+red[3][1];
        ws[2*NBLK + blk] = red[0][2]+red[1][2]+red[2][2]+red[3][2];
        ws[3*NBLK + blk] = red[0][3]+red[1][3]+red[2][3]+red[3][3];
        ws[4*NBLK + blk] = red[0][4]+red[1][4]+red[2][4]+red[3][4];
    }
}

__global__ __launch_bounds__(256) void fin_kernel(const float* __restrict__ ws, float* __restrict__ out){
    const int tid = threadIdx.x;
    float s[5] = {0.f,0.f,0.f,0.f,0.f};
    for (int i = tid; i < NBLK; i += 256){
        #pragma unroll
        for (int c=0;c<5;c++) s[c] += ws[c*NBLK + i];
    }
    for (int off=32; off>0; off>>=1){
        #pragma unroll
        for (int c=0;c<5;c++) s[c] += __shfl_down(s[c], off);
    }
    __shared__ float red[4][5];
    const int wid = tid >> 6, ln = tid & 63;
    if (ln == 0){ for (int c=0;c<5;c++) red[wid][c] = s[c]; }
    __syncthreads();
    if (tid == 0){
        float t_xy  = red[0][0]+red[1][0]+red[2][0]+red[3][0];
        float t_wh  = red[0][1]+red[1][1]+red[2][1]+red[3][1];
        float t_obj = red[0][2]+red[1][2]+red[2][2]+red[3][2];
        float t_cls = red[0][3]+red[1][3]+red[2][3]+red[3][3];
        float t_l2  = red[0][4]+red[1][4]+red[2][4]+red[3][4];
        out[0] = t_xy + t_wh + t_obj + t_cls;
        out[1] = t_xy; out[2] = t_wh; out[3] = t_obj; out[4] = t_cls; out[5] = t_l2;
    }
}

extern "C" void kernel_launch(void* const* d_in, const int* in_sizes, int n_in,
                              void* d_out, int out_size, void* d_ws, size_t ws_size,
                              hipStream_t stream) {
    const float* x0 = (const float*)d_in[0];
    const float* x1 = (const float*)d_in[1];
    const float* x2 = (const float*)d_in[2];
    const float* labels = (const float*)d_in[3];
    float* out = (float*)d_out;
    float* ws = (float*)d_ws;   // 5 * NBLK floats

    main_kernel<<<dim3(NBX, BATCH), 256, 0, stream>>>(x0, x1, x2, labels, ws);
    fin_kernel<<<1, 256, 0, stream>>>(ws, out);
}

// Round 7
// 23.992 us; speedup vs baseline: 3.0232x; 1.0814x over previous
//
#include <hip/hip_runtime.h>

#define BATCH 16
#define TT 60
#define NCLS 80
// 512 cells per block: lvl0 ceil(17328/512)=34, lvl1 ceil(4332/512)=9, lvl2 ceil(1083/512)=3
#define NB0 34
#define NB1 9
#define NB2 3
#define NBX (NB0 + NB1 + NB2)
#define NBLK (NBX * BATCH)

__constant__ float c_aw[9] = {12.f,19.f,40.f,36.f,76.f,72.f,142.f,192.f,459.f};
__constant__ float c_ah[9] = {16.f,36.f,28.f,75.f,55.f,146.f,110.f,243.f,401.f};

__device__ __forceinline__ float sigf(float x){ return 1.0f/(1.0f+expf(-x)); }
__device__ __forceinline__ float clogf_(float x){ return fmaxf(logf(x), -100.0f); }
__device__ __forceinline__ float bcef(float p, float t){
    return -(t*clogf_(p) + (1.0f-t)*clogf_(1.0f-p));
}

// 2 cells/thread; 2 barriers total; class channels processed wave-locally via ballot.
__global__ __launch_bounds__(256) void main_kernel(
    const float* __restrict__ x0, const float* __restrict__ x1,
    const float* __restrict__ x2, const float* __restrict__ labels,
    float* __restrict__ ws)
{
    const int bx = blockIdx.x, b = blockIdx.y, tid = threadIdx.x;
    int lvl, lb, fs;
    const float* x;
    if (bx < NB0)            { lvl = 0; lb = bx;             x = x0; fs = 76; }
    else if (bx < NB0 + NB1) { lvl = 1; lb = bx - NB0;       x = x1; fs = 38; }
    else                     { lvl = 2; lb = bx - NB0 - NB1; x = x2; fs = 19; }
    const float invs = 1.0f/(float)(8 << lvl);     // exact (pow2)
    const int fs2 = fs*fs;
    const int ncell = 3*fs2;
    const int lin0 = lb*512 + tid;
    const int lin1 = lin0 + 256;

    __shared__ float  s_atan[9];
    __shared__ float4 s_box[TT];
    __shared__ int    s_mcell[TT], s_mcls[TT];
    __shared__ float  s_vx[TT], s_vy[TT], s_vw[TT], s_vh[TT], s_sc[TT];
    __shared__ int    s_nv, s_nm;

    // ---- stage A: label loads FIRST (wave0 waits these without draining x-loads)
    float l0=0,l1=0,l2=0,l3=0,l4=0;
    if (tid < TT) {
        const float* lab = labels + ((size_t)b*TT + tid)*5;
        l0=lab[0]; l1=lab[1]; l2=lab[2]; l3=lab[3]; l4=lab[4];
    }
    if (tid < 9) s_atan[tid] = atanf(c_aw[tid]/c_ah[tid]);   // wave0-internal

    // then the 2 cells' channel loads (consumed after the barrier; latency hidden by stage B)
    float v0a=0,v1a=0,v2a=0,v3a=0,v4a=0, v0b=0,v1b=0,v2b=0,v3b=0,v4b=0;
    int a0=0,rem0=0,ci0=0,cj0=0, a1=0,rem1=0,ci1=0,cj1=0;
    if (lin0 < ncell) {
        a0 = lin0/fs2; rem0 = lin0 - a0*fs2; cj0 = rem0/fs; ci0 = rem0 - cj0*fs;
        const float* xb = x + ((size_t)b*255 + a0*85)*(size_t)fs2 + rem0;
        v0a = xb[0]; v1a = xb[(size_t)fs2]; v2a = xb[(size_t)2*fs2];
        v3a = xb[(size_t)3*fs2]; v4a = xb[(size_t)4*fs2];
    }
    if (lin1 < ncell) {
        a1 = lin1/fs2; rem1 = lin1 - a1*fs2; cj1 = rem1/fs; ci1 = rem1 - cj1*fs;
        const float* xb = x + ((size_t)b*255 + a1*85)*(size_t)fs2 + rem1;
        v0b = xb[0]; v1b = xb[(size_t)fs2]; v2b = xb[(size_t)2*fs2];
        v3b = xb[(size_t)3*fs2]; v4b = xb[(size_t)4*fs2];
    }

    // ---- stage B: per-truth prep on wave 0 (no preceding barrier needed:
    // labels/s_atan are produced & consumed within wave 0)
    if (tid < 64) {
        bool valid=false, best=false;
        float tx=0,ty=0,tw=0,th=0;
        int best_all=0;
        if (tid < TT) {
            valid = ((((l0+l1)+l2)+l3)+l4) > 0.0f;
            tx = (l2+l0)*(0.5f*invs);
            ty = (l3+l1)*(0.5f*invs);
            tw = (l2-l0)*invs;
            th = (l3-l1)*invs;
            if (valid) {
                float ta = atanf(tw/th);
                float twth = tw*th;
                float bestv = 0.0f;
                for (int k=0;k<9;k++){
                    float wb=c_aw[k]*invs, hb=c_ah[k]*invs;
                    float iw=fminf(tw,wb), ih=fminf(th,hb);
                    float en=(iw>0.f && ih>0.f)?1.f:0.f;
                    float ai=iw*ih*en;
                    float au=twth+wb*hb-ai;
                    float iou=ai/au;
                    float mw=fmaxf(tw,wb), mh=fmaxf(th,hb);
                    float c2=mw*mw+mh*mh+1e-16f;
                    float rho2=((tw-wb)*(tw-wb)+(th-hb)*(th-hb))*0.25f;
                    float da=ta-s_atan[k];
                    float v=0.40528473456935109f*da*da;     // 4/pi^2
                    float alpha=v/((1.f-iou)+v);
                    float cv=iou-(rho2/c2+v*alpha);
                    if (k==0 || cv>bestv){ bestv=cv; best_all=k; }  // first-max wins
                }
            }
        }
        int bn = best_all % 3;
        best = valid && ((best_all/3) == lvl);
        unsigned long long vm = __ballot(valid);
        unsigned long long bm = __ballot(best);
        unsigned long long below = (tid==0) ? 0ULL : ((1ULL<<tid)-1ULL);
        if (valid){
            int r = __popcll(vm & below);
            s_box[r] = make_float4(tx-0.5f*tw, ty-0.5f*th, tx+0.5f*tw, ty+0.5f*th);
        }
        if (best){
            int r = __popcll(bm & below);
            int ti=(int)tx, tj=(int)ty;
            int ii = ti<0?0:(ti>fs-1?fs-1:ti);
            int jj = tj<0?0:(tj>fs-1?fs-1:tj);
            s_mcell[r] = (bn*fs+jj)*fs+ii;
            s_mcls[r]  = (int)l4;
            s_sc[r]    = sqrtf(2.f - tw*th/(float)(fs*fs));
            s_vx[r]    = tx - truncf(tx);
            s_vy[r]    = ty - truncf(ty);
            float aw = c_aw[3*lvl+bn]*invs, ah = c_ah[3*lvl+bn]*invs;
            s_vw[r]    = logf(tw/aw + 1e-16f);
            s_vh[r]    = logf(th/ah + 1e-16f);
        }
        if (tid==0){ s_nv = __popcll(vm); s_nm = __popcll(bm); }
    }
    __syncthreads();   // barrier 1 of 2: publishes s_*; also drains x-loads (arrived during B)

    // ---- stage C: per-cell loss for both cells + wave-local class processing
    const int nv = s_nv, nm = s_nm;
    float lxy=0.f, lwh=0.f, lobj=0.f, lcls=0.f, ll2=0.f;
    int mt0 = -1, mt1 = -1;
    int qoff0 = 0, qoff1 = 0, cls0 = 0, cls1 = 0;
    const bool c0 = (lin0 < ncell), c1 = (lin1 < ncell);
    float v2a_ = v2a, v3a_ = v3a, v2b_ = v2b, v3b_ = v3b;
    if (c0 | c1) {
        const float sxa = sigf(v0a), sya = sigf(v1a), soa = sigf(v4a);
        const float sxb = sigf(v0b), syb = sigf(v1b), sob = sigf(v4b);
        const float awa = c_aw[3*lvl+a0]*invs, aha = c_ah[3*lvl+a0]*invs;
        const float awb = c_aw[3*lvl+a1]*invs, ahb = c_ah[3*lvl+a1]*invs;
        const float pxa = sxa + (float)ci0, pya = sya + (float)cj0;
        const float pxb = sxb + (float)ci1, pyb = syb + (float)cj1;
        const float pwa = expf(v2a_)*awa, pha = expf(v3a_)*aha;
        const float pwb = expf(v2b_)*awb, phb = expf(v3b_)*ahb;
        const float apa = pwa*pha, apb = pwb*phb;

        for (int k=0;k<nm;k++){                    // last match wins
            int mc = s_mcell[k];
            if (mc == lin0) mt0 = k;
            if (mc == lin1) mt1 = k;
        }

        bool iga = false, igb = false;             // IoU>0.5 <=> 3*ai > ap+at (ap>0)
        if (nm > 0) {
            const float xla = pxa-0.5f*pwa, xra = pxa+0.5f*pwa;
            const float yla = pya-0.5f*pha, yra = pya+0.5f*pha;
            const float xlb = pxb-0.5f*pwb, xrb = pxb+0.5f*pwb;
            const float ylb = pyb-0.5f*phb, yrb = pyb+0.5f*phb;
            #pragma unroll 4
            for (int t=0;t<nv;t++){
                float4 tb = s_box[t];
                float at2 = (tb.z-tb.x)*(tb.w-tb.y);
                float wa = fmaxf(fminf(xra,tb.z) - fmaxf(xla,tb.x), 0.f);
                float ha = fmaxf(fminf(yra,tb.w) - fmaxf(yla,tb.y), 0.f);
                float wb = fmaxf(fminf(xrb,tb.z) - fmaxf(xlb,tb.x), 0.f);
                float hb = fmaxf(fminf(yrb,tb.w) - fmaxf(ylb,tb.y), 0.f);
                iga = iga || (3.f*(wa*ha) > apa+at2);
                igb = igb || (3.f*(wb*hb) > apb+at2);
            }
        }
        if (c0) {
            float om = (nm>0) ? (iga ? 0.f : 1.f) : 1.f;
            float t4 = 0.f;
            if (mt0 >= 0){ om = 1.f; t4 = 1.f; }
            float oo = soa*om, to = t4*om;
            lobj += bcef(oo, to);
            float d = oo - to; ll2 += d*d;
            if (mt0 >= 0) {
                float sc = s_sc[mt0], w2 = sc*sc;
                float mvx = s_vx[mt0], mvy = s_vy[mt0];
                lxy += w2*(bcef(sxa,mvx) + bcef(sya,mvy));
                float dx = sxa-mvx, dy = sya-mvy;
                float dw = sc*(v2a_ - s_vw[mt0]);
                float dh = sc*(v3a_ - s_vh[mt0]);
                lwh += 0.5f*(dw*dw + dh*dh);
                ll2 += dx*dx + dy*dy + dw*dw + dh*dh;
                qoff0 = (a0*85+5)*fs2 + rem0;
                cls0  = s_mcls[mt0];
            }
        }
        if (c1) {
            float om = (nm>0) ? (igb ? 0.f : 1.f) : 1.f;
            float t4 = 0.f;
            if (mt1 >= 0){ om = 1.f; t4 = 1.f; }
            float oo = sob*om, to = t4*om;
            lobj += bcef(oo, to);
            float d = oo - to; ll2 += d*d;
            if (mt1 >= 0) {
                float sc = s_sc[mt1], w2 = sc*sc;
                float mvx = s_vx[mt1], mvy = s_vy[mt1];
                lxy += w2*(bcef(sxb,mvx) + bcef(syb,mvy));
                float dx = sxb-mvx, dy = syb-mvy;
                float dw = sc*(v2b_ - s_vw[mt1]);
                float dh = sc*(v3b_ - s_vh[mt1]);
                lwh += 0.5f*(dw*dw + dh*dh);
                ll2 += dx*dx + dy*dy + dw*dw + dh*dh;
                qoff1 = (a1*85+5)*fs2 + rem1;
                cls1  = s_mcls[mt1];
            }
        }
    }

    // ---- wave-local class channels: each wave processes its own matched cells
    const int ln = tid & 63;
    const size_t bbase = (size_t)b*255*(size_t)fs2;
    unsigned long long mb0 = __ballot(mt0 >= 0);
    unsigned long long mb1 = __ballot(mt1 >= 0);
    while (mb0 | mb1) {
        int src, qoff, cc;
        if (mb0) {
            src = __ffsll(mb0) - 1; mb0 &= mb0 - 1;
            qoff = __shfl(qoff0, src); cc = __shfl(cls0, src);
        } else {
            src = __ffsll(mb1) - 1; mb1 &= mb1 - 1;
            qoff = __shfl(qoff1, src); cc = __shfl(cls1, src);
        }
        const size_t base = bbase + (size_t)qoff;
        float p = sigf(x[base + (size_t)ln*fs2]);
        float tt = (ln==cc) ? 1.f : 0.f;
        lcls += bcef(p, tt);
        float dd = p - tt; ll2 += dd*dd;
        if (ln < NCLS-64) {
            int c = 64+ln;
            p = sigf(x[base + (size_t)c*fs2]);
            tt = (c==cc) ? 1.f : 0.f;
            lcls += bcef(p, tt);
            dd = p - tt; ll2 += dd*dd;
        }
    }

    // ---- block reduction + per-block partial stores
    for (int off=32; off>0; off>>=1){
        lxy  += __shfl_down(lxy,  off);
        lwh  += __shfl_down(lwh,  off);
        lobj += __shfl_down(lobj, off);
        lcls += __shfl_down(lcls, off);
        ll2  += __shfl_down(ll2,  off);
    }
    __shared__ float red[4][5];
    const int wid = tid >> 6;
    if (ln == 0){ red[wid][0]=lxy; red[wid][1]=lwh; red[wid][2]=lobj; red[wid][3]=lcls; red[wid][4]=ll2; }
    __syncthreads();   // barrier 2 of 2
    if (tid == 0){
        const int blk = b*NBX + bx;
        ws[0*NBLK + blk] = red[0][0]+red[1][0]+red[2][0]+red[3][0];
        ws[1*NBLK + blk] = red[0][1]+red[1][1]+red[2][1]+red[3][1];
        ws[2*NBLK + blk] = red[0][2]+red[1][2]+red[2][2]+red[3][2];
        ws[3*NBLK + blk] = red[0][3]+red[1][3]+red[2][3]+red[3][3];
        ws[4*NBLK + blk] = red[0][4]+red[1][4]+red[2][4]+red[3][4];
    }
}

__global__ __launch_bounds__(256) void fin_kernel(const float* __restrict__ ws, float* __restrict__ out){
    const int tid = threadIdx.x;
    float s[5] = {0.f,0.f,0.f,0.f,0.f};
    for (int i = tid; i < NBLK; i += 256){
        #pragma unroll
        for (int c=0;c<5;c++) s[c] += ws[c*NBLK + i];
    }
    for (int off=32; off>0; off>>=1){
        #pragma unroll
        for (int c=0;c<5;c++) s[c] += __shfl_down(s[c], off);
    }
    __shared__ float red[4][5];
    const int wid = tid >> 6, ln = tid & 63;
    if (ln == 0){ for (int c=0;c<5;c++) red[wid][c] = s[c]; }
    __syncthreads();
    if (tid == 0){
        float t_xy  = red[0][0]+red[1][0]+red[2][0]+red[3][0];
        float t_wh  = red[0][1]+red[1][1]+red[2][1]+red[3][1];
        float t_obj = red[0][2]+red[1][2]+red[2][2]+red[3][2];
        float t_cls = red[0][3]+red[1][3]+red[2][3]+red[3][3];
        float t_l2  = red[0][4]+red[1][4]+red[2][4]+red[3][4];
        out[0] = t_xy + t_wh + t_obj + t_cls;
        out[1] = t_xy; out[2] = t_wh; out[3] = t_obj; out[4] = t_cls; out[5] = t_l2;
    }
}

extern "C" void kernel_launch(void* const* d_in, const int* in_sizes, int n_in,
                              void* d_out, int out_size, void* d_ws, size_t ws_size,
                              hipStream_t stream) {
    const float* x0 = (const float*)d_in[0];
    const float* x1 = (const float*)d_in[1];
    const float* x2 = (const float*)d_in[2];
    const float* labels = (const float*)d_in[3];
    float* out = (float*)d_out;
    float* ws = (float*)d_ws;   // 5 * NBLK floats

    main_kernel<<<dim3(NBX, BATCH), 256, 0, stream>>>(x0, x1, x2, labels, ws);
    fin_kernel<<<1, 256, 0, stream>>>(ws, out);
}